// Round 10
// baseline (165.742 us; speedup 1.0000x reference)
//
#include <hip/hip_runtime.h>
#include <hip/hip_bf16.h>

#define BS 4
#define SEQ 2048
#define DIM 512
#define HEADS 8
#define HD 64
#define ROWS (BS*SEQ)   // 8192
// (1/sqrt(64)) * log2(e) folded into K at projection time
#define SCL2E 0.1803368801111244f
#define NEGB (-1.4426950408889634e6f)   // -1e6 * log2(e)

typedef __attribute__((ext_vector_type(8))) short bf16x8;
typedef __attribute__((ext_vector_type(4))) short bf16x4;
typedef __attribute__((ext_vector_type(4))) float floatx4;
typedef unsigned short u16;
typedef unsigned int u32;

#if defined(__has_builtin)
# if __has_builtin(__builtin_amdgcn_mfma_f32_16x16x16bf16_1k)
#  define HAVE_MFMA16 1
# endif
#endif
#ifndef HAVE_MFMA16
# define HAVE_MFMA16 0
#endif

__device__ __forceinline__ u16 f2bf(float f) {
    union { float f; unsigned u; } v; v.f = f;
    unsigned r = v.u + 0x7fff + ((v.u >> 16) & 1);
    return (u16)(r >> 16);
}

__device__ __forceinline__ unsigned pack2bf(float a, float b) {
#if __has_builtin(__builtin_amdgcn_cvt_pk_bf16_f32)
    typedef __attribute__((ext_vector_type(2))) __bf16 bf2;
    union { bf2 v; unsigned u; } cv;
    cv.v = __builtin_amdgcn_cvt_pk_bf16_f32(a, b);
    return cv.u;
#else
    return (unsigned)f2bf(a) | ((unsigned)f2bf(b) << 16);
#endif
}

__device__ __forceinline__ float fexp2(float x) {
#if __has_builtin(__builtin_amdgcn_exp2f)
    return __builtin_amdgcn_exp2f(x);     // raw v_exp_f32
#else
    return __expf(x * 0.6931471805599453f);
#endif
}

// async global->LDS, 16B per lane. g is PER-LANE global addr, l is wave-uniform.
__device__ __forceinline__ void gload16(const u16* g, u16* l) {
    __builtin_amdgcn_global_load_lds(
        (const __attribute__((address_space(1))) u32*)g,
        (__attribute__((address_space(3))) u32*)l, 16, 0, 0);
}

// ---------------- fp32 -> bf16 conversion; mask -> exp2-domain bias ---------
__global__ __launch_bounds__(256) void convert_all(
    const float* __restrict__ x, const float* __restrict__ Wq,
    const float* __restrict__ Wk, const float* __restrict__ Wv,
    const float* __restrict__ Wo, const int* __restrict__ mask,
    u16* __restrict__ xb, u16* __restrict__ wqb,
    u16* __restrict__ wkb, u16* __restrict__ wvb,
    u16* __restrict__ wob, float* __restrict__ biasf)
{
    int i = blockIdx.x * 256 + threadIdx.x;
    if (i < 1048576 + 262144) {
        const float* src; u16* dst; int off;
        if (i < 1048576) { src = x; dst = xb; off = i; }
        else {
            int j = i - 1048576; int seg = j >> 16; off = j & 65535;
            src = seg == 0 ? Wq : seg == 1 ? Wk : seg == 2 ? Wv : Wo;
            dst = seg == 0 ? wqb : seg == 1 ? wkb : seg == 2 ? wvb : wob;
        }
        float4 v = ((const float4*)src)[off];
        ushort4 o;
        o.x = f2bf(v.x); o.y = f2bf(v.y); o.z = f2bf(v.z); o.w = f2bf(v.w);
        ((ushort4*)dst)[off] = o;
    } else {
        int jb = i - 1310720;                      // 0..2047
        int4 mv = ((const int4*)mask)[jb];
        float4 bo;
        bo.x = (mv.x == 1) ? 0.f : NEGB;
        bo.y = (mv.y == 1) ? 0.f : NEGB;
        bo.z = (mv.z == 1) ? 0.f : NEGB;
        bo.w = (mv.w == 1) ? 0.f : NEGB;
        ((float4*)biasf)[jb] = bo;
    }
}

// ---------------- fused QKV GEMM: C = x @ [Wq;Wk;Wv]^T ----------------------
// V epilogue (HAVE_MFMA16): per-lane 32B chunks for direct reg loads in flash:
//   off = tile*4096 + wf*1024 + (quadf*16 + l16f)*16 + ct*4 + j
//   element (key = t*64 + wf*16 + quadf*4 + j, d = ct*16 + l16f)
__global__ __launch_bounds__(256, 3) void gemm_qkv_fused(
    const u16* __restrict__ A, const u16* __restrict__ Wcat,
    u16* __restrict__ Oq, u16* __restrict__ Okf, u16* __restrict__ Ovf)
{
    __shared__ u16 ldsA[8192];   // 128 rows x 64, chunk i (1KB) = rows 8i..8i+7
    __shared__ u16 ldsB[8192];

    int n0 = blockIdx.x * 128;   // 0..1535
    int m0 = blockIdx.y * 128;
    int tid = threadIdx.x;
    int w = tid >> 6, lane = tid & 63, quad = lane >> 4, l16 = lane & 15;
    int mo = (w & 1) * 64, no = (w >> 1) * 64;
    int l7 = l16 & 7;

    int sr = lane >> 3, sc = lane & 7, gc = sc ^ sr;   // staging row/chunk-swz
    const u16* gA0 = A    + (long)(m0 + sr) * DIM + gc * 8;
    const u16* gB0 = Wcat + (long)(n0 + sr) * DIM + gc * 8;

    floatx4 acc[4][4];
    #pragma unroll
    for (int mt = 0; mt < 4; mt++)
        #pragma unroll
        for (int nt = 0; nt < 4; nt++) acc[mt][nt] = (floatx4){0.f,0.f,0.f,0.f};

    for (int k0 = 0; k0 < DIM; k0 += 64) {
        #pragma unroll
        for (int i = 0; i < 4; i++) {
            int ch = w * 4 + i;
            gload16(gA0 + (long)ch * 8 * DIM + k0, &ldsA[ch * 512]);
            gload16(gB0 + (long)ch * 8 * DIM + k0, &ldsB[ch * 512]);
        }
        __syncthreads();

        #pragma unroll
        for (int kc = 0; kc < 2; kc++) {
            int swz = ((kc * 4 + quad) ^ l7) * 8;
            bf16x8 af[4], bf[4];
            #pragma unroll
            for (int t4 = 0; t4 < 4; t4++) {
                af[t4] = *(const bf16x8*)&ldsA[(mo + t4*16 + l16) * 64 + swz];
                bf[t4] = *(const bf16x8*)&ldsB[(no + t4*16 + l16) * 64 + swz];
            }
            #pragma unroll
            for (int mt = 0; mt < 4; mt++)
                #pragma unroll
                for (int nt = 0; nt < 4; nt++)
                    acc[mt][nt] = __builtin_amdgcn_mfma_f32_16x16x32_bf16(
                        af[mt], bf[nt], acc[mt][nt], 0, 0, 0);
        }
        __syncthreads();
    }

    int seg = n0 >> 9;    // block-uniform: 0=Q 1=K 2=V
    if (seg == 0) {
        #pragma unroll
        for (int mt = 0; mt < 4; mt++)
            #pragma unroll
            for (int nt = 0; nt < 4; nt++)
                #pragma unroll
                for (int r = 0; r < 4; r++) {
                    int row = m0 + mo + mt*16 + quad*4 + r;      // b*SEQ+n
                    int col9 = (n0 + no + nt*16 + l16) & 511;    // h*64+d
                    int b = row >> 11, n = row & 2047, h = col9 >> 6, d = col9 & 63;
                    Oq[(((long)(b * HEADS + h) * SEQ + n) << 6) + d] = f2bf(acc[mt][nt][r]);
                }
    } else if (seg == 1) {
        #pragma unroll
        for (int mt = 0; mt < 4; mt++)
            #pragma unroll
            for (int nt = 0; nt < 4; nt++)
                #pragma unroll
                for (int r = 0; r < 4; r++) {
                    int row = m0 + mo + mt*16 + quad*4 + r;
                    int col9 = (n0 + no + nt*16 + l16) & 511;
                    int b = row >> 11, keyn = row & 2047, h = col9 >> 6, dd = col9 & 63;
                    int kt = keyn >> 6, ntk = (keyn >> 4) & 3, l16k = keyn & 15;
                    int g = dd >> 5, quadk = (dd >> 3) & 3, j = dd & 7;
                    long offv = ((long)((b*HEADS + h)*32 + kt) << 12)
                              + ((ntk*2 + g) << 9) + ((quadk*16 + l16k) << 3) + j;
                    Okf[offv] = f2bf(acc[mt][nt][r] * SCL2E);
                }
    } else {
#if HAVE_MFMA16
        // V in per-lane-32B order (see header comment)
        #pragma unroll
        for (int mt = 0; mt < 4; mt++)
            #pragma unroll
            for (int nt = 0; nt < 4; nt++) {
                int rowb = m0 + mo + mt*16 + quad*4;
                int col9 = (n0 + no + nt*16 + l16) & 511;
                int b = rowb >> 11, keyn = rowb & 2047, h = col9 >> 6, dd = col9 & 63;
                int kt = keyn >> 6;
                int wf = (keyn >> 4) & 3, quadf = (keyn >> 2) & 3;   // j = r
                int ctf = dd >> 4, l16f = dd & 15;
                long offv = ((long)((b*HEADS + h)*32 + kt) << 12)
                          + (wf << 10) + ((quadf*16 + l16f) << 4) + (ctf << 2);
                ushort4 st;
                st.x = f2bf(acc[mt][nt][0]); st.y = f2bf(acc[mt][nt][1]);
                st.z = f2bf(acc[mt][nt][2]); st.w = f2bf(acc[mt][nt][3]);
                *(ushort4*)&Ovf[offv] = st;
            }
#else
        #pragma unroll
        for (int mt = 0; mt < 4; mt++)
            #pragma unroll
            for (int nt = 0; nt < 4; nt++) {
                int rowb = m0 + mo + mt*16 + quad*4;
                int col9 = (n0 + no + nt*16 + l16) & 511;
                int b = rowb >> 11, keyn = rowb & 2047, h = col9 >> 6, dd = col9 & 63;
                int kt = keyn >> 6, g = (keyn >> 5) & 1, quadv = (keyn >> 3) & 3, jk = keyn & 7;
                int ctv = dd >> 4, l16v = dd & 15;
                long offv = ((long)((b*HEADS + h)*32 + kt) << 12)
                          + ((ctv*2 + g) << 9) + ((quadv*16 + l16v) << 3) + jk;
                ushort4 st;
                st.x = f2bf(acc[mt][nt][0]); st.y = f2bf(acc[mt][nt][1]);
                st.z = f2bf(acc[mt][nt][2]); st.w = f2bf(acc[mt][nt][3]);
                *(ushort4*)&Ovf[offv] = st;
            }
#endif
    }
}

#if HAVE_MFMA16
// ---------------- flash attention: key-split, register-direct (R8 struct) ---
// R10 delta vs R8: V is loaded directly at its in-tile use point (not rolling-
// prefetched) -> ~16 fewer live VGPRs, crossing the 170-reg 3-waves/SIMD
// boundary (granule-16 model: 96+80=176 -> 80+80=160). K + bias stay rolling.
__global__ __launch_bounds__(256, 3) void flash_attn(
    const u16* __restrict__ Q, const u16* __restrict__ Kf,
    const u16* __restrict__ Vf, const float* __restrict__ biasf,
    u16* __restrict__ ctx)
{
    __shared__ float red[4352];   // [0,4096) O slots (1024 floatx4), [4096,4352) lsum

    int bx = blockIdx.x;
    // decode XCD swizzle: bx = (g&7) + 8*((g>>3)*32 + i), g = b*8+h, i = q-block
    int c  = bx & 7, s = bx >> 3;
    int g  = ((s >> 5) << 3) | c;
    int i  = s & 31;
    int q0 = i * 64;
    int h  = g & 7;
    int b  = g >> 3;
    int bh = b * HEADS + h;

    int tid = threadIdx.x;
    int w = tid >> 6, lane = tid & 63, quad = lane >> 4, l16 = lane & 15;

    // Q B-frags for all 4 q-tiles (wave needs all 64 q)
    bf16x8 qb[4][2];
    #pragma unroll
    for (int nt = 0; nt < 4; nt++) {
        const u16* qp = Q + ((long)bh * SEQ + q0 + nt*16 + l16) * HD + quad * 8;
        qb[nt][0] = *(const bf16x8*)(qp);
        qb[nt][1] = *(const bf16x8*)(qp + 32);
    }

    const u16* Kbh = Kf + ((long)bh << 17) + w*1024 + lane*8;    // + t*4096
    const u16* Vbh = Vf + ((long)bh << 17) + w*1024 + lane*16;   // + t*4096
    const float* bb = biasf + b * SEQ + w*16 + quad*4;           // + t*64

    // ones-column B operand: 1.0 only for n == 0 (lanes l16==0), all k
    short one_s = (l16 == 0) ? (short)0x3F80 : (short)0;
    bf16x4 onesb = { one_s, one_s, one_s, one_s };

    // rolling preload: K + bias only
    bf16x8 ka0 = *(const bf16x8*)(Kbh);
    bf16x8 ka1 = *(const bf16x8*)(Kbh + 512);
    float4 bv  = *(const float4*)(bb);

    floatx4 o[4][4];
    floatx4 o5[4];
    #pragma unroll
    for (int nt = 0; nt < 4; nt++) {
        #pragma unroll
        for (int ct = 0; ct < 4; ct++) o[nt][ct] = (floatx4){0.f,0.f,0.f,0.f};
        o5[nt] = (floatx4){0.f,0.f,0.f,0.f};
    }

    #pragma unroll 2
    for (int t = 0; t < 32; t++) {
        // prefetch next K tile + bias into fresh registers
        bf16x8 ka0n = ka0, ka1n = ka1;
        float4 bvn = bv;
        if (t < 31) {
            const u16* kp = Kbh + (long)(t+1)*4096;
            ka0n = *(const bf16x8*)(kp);
            ka1n = *(const bf16x8*)(kp + 512);
            bvn  = *(const float4*)(bb + (t+1)*64);
        }

        // V: direct in-tile load (use point is after QK+exp -> latency covered)
        const u16* vp = Vbh + (long)t*4096;
        bf16x8 vlo = *(const bf16x8*)(vp);
        bf16x8 vhi = *(const bf16x8*)(vp + 8);
        union { bf16x8 v8; bf16x4 v4[2]; } uvl, uvh;
        uvl.v8 = vlo; uvh.v8 = vhi;
        bf16x4 vb[4] = { uvl.v4[0], uvl.v4[1], uvh.v4[0], uvh.v4[1] };

        #pragma unroll
        for (int nt = 0; nt < 4; nt++) {
            // S^T[16key][16q] = K.Q^T + bias (C-init; key=quad*4+r, q=l16)
            floatx4 s2;
            s2[0] = bv.x; s2[1] = bv.y; s2[2] = bv.z; s2[3] = bv.w;
            s2 = __builtin_amdgcn_mfma_f32_16x16x32_bf16(ka0, qb[nt][0], s2, 0, 0, 0);
            s2 = __builtin_amdgcn_mfma_f32_16x16x32_bf16(ka1, qb[nt][1], s2, 0, 0, 0);
            float p0 = fexp2(s2[0]);
            float p1 = fexp2(s2[1]);
            float p2 = fexp2(s2[2]);
            float p3 = fexp2(s2[3]);
            // C layout (q=l16, key=quad*4+r) == 16x16x16 A layout (m=l16, k=quad*4+j)
            union { bf16x4 v; unsigned u[2]; } pu;
            pu.u[0] = pack2bf(p0, p1);
            pu.u[1] = pack2bf(p2, p3);
            #pragma unroll
            for (int ct = 0; ct < 4; ct++)
                o[nt][ct] = __builtin_amdgcn_mfma_f32_16x16x16bf16_1k(
                    pu.v, vb[ct], o[nt][ct], 0, 0, 0);
            // denominator on the matrix pipe (rows q=quad*4+r at col l16==0)
            o5[nt] = __builtin_amdgcn_mfma_f32_16x16x16bf16_1k(
                pu.v, onesb, o5[nt], 0, 0, 0);
        }

        ka0 = ka0n; ka1 = ka1n; bv = bvn;
    }

    __syncthreads();
    float* ldsf = red;
    floatx4* ldsv = (floatx4*)red;

    // publish per-(wave, q) partial denominators from lanes l16==0
    if (l16 == 0) {
        #pragma unroll
        for (int nt = 0; nt < 4; nt++)
            #pragma unroll
            for (int r = 0; r < 4; r++)
                ldsf[4096 + w*64 + nt*16 + quad*4 + r] = o5[nt][r];
    }
    __syncthreads();

    // O rotation: 3 rounds; wave w ends owning full O for q-tile nt==w
    #pragma unroll
    for (int i2 = 1; i2 < 4; i2++) {
        int tslot = (w + i2) & 3;          // wave-uniform
        #pragma unroll
        for (int nt = 0; nt < 4; nt++)
            if (nt == tslot) {
                #pragma unroll
                for (int ct = 0; ct < 4; ct++)
                    ldsv[nt*256 + ct*64 + lane] = o[nt][ct];
            }
        __syncthreads();
        #pragma unroll
        for (int nt = 0; nt < 4; nt++)
            if (nt == w) {
                #pragma unroll
                for (int ct = 0; ct < 4; ct++) {
                    floatx4 v = ldsv[nt*256 + ct*64 + lane];
                    o[nt][ct] += v;
                }
            }
        __syncthreads();
    }

    // epilogue: wave w owns q = q0 + w*16 + quad*4 + r; d = ct*16 + l16
    #pragma unroll
    for (int nt = 0; nt < 4; nt++) {
        if (nt != w) continue;            // wave-uniform
        float inv[4];
        #pragma unroll
        for (int r = 0; r < 4; r++) {
            int q = w*16 + quad*4 + r;
            float sden = ldsf[4096 + q] + ldsf[4096 + 64 + q]
                       + ldsf[4096 + 128 + q] + ldsf[4096 + 192 + q];
            inv[r] = 1.0f / sden;
        }
        #pragma unroll
        for (int ct = 0; ct < 4; ct++) {
            int col = h * HD + ct*16 + l16;
            long rb = (long)(b * SEQ + q0 + w*16 + quad*4);
            #pragma unroll
            for (int r = 0; r < 4; r++)
                ctx[(rb + r) * DIM + col] = f2bf(o[nt][ct][r] * inv[r]);
        }
    }
}
#else
// ---------------- fallback: R5 flash attention ------------------------------
__global__ __launch_bounds__(256, 4) void flash_attn(
    const u16* __restrict__ Q, const u16* __restrict__ Kf,
    const u16* __restrict__ Vf, const float* __restrict__ biasf,
    u16* __restrict__ ctx)
{
    __shared__ u16 lds[20480];

    int bx = blockIdx.x;
    int q0 = (bx & 31) * 64;
    int h  = (bx >> 5) & 7;
    int b  = bx >> 8;
    int bh = b * HEADS + h;

    int tid = threadIdx.x;
    int w = tid >> 6, lane = tid & 63, quad = lane >> 4, l16 = lane & 15;

    const u16* Qp = Q + ((long)bh * SEQ + q0 + w*16 + l16) * HD + quad * 8;
    bf16x8 qb0 = *(const bf16x8*)(Qp);
    bf16x8 qb1 = *(const bf16x8*)(Qp + 32);

    const u16* Kbh = Kf + ((long)bh << 17);
    const u16* Vbh = Vf + ((long)bh << 17);
    const float* bbase = biasf + b * SEQ + quad * 4;

    u16* Prow = &lds[16384 + w * 1024 + l16 * 64];
    int swz = l16 & 7;

    {
        const u16* gk = Kbh + (2*w)*512 + lane*8;
        const u16* gv = Vbh + (2*w)*512 + lane*8;
        gload16(gk,       &lds[(2*w)*512]);
        gload16(gk + 512, &lds[(2*w+1)*512]);
        gload16(gv,       &lds[8192 + (2*w)*512]);
        gload16(gv + 512, &lds[8192 + (2*w+1)*512]);
    }
    __syncthreads();

    floatx4 o[4];
    #pragma unroll
    for (int ct = 0; ct < 4; ct++) o[ct] = (floatx4){0.f, 0.f, 0.f, 0.f};
    float lsum = 0.f;

    for (int t = 0; t < 32; t++) {
        int cur = t & 1;
        if (t < 31) {
            long tb = (long)(t + 1) << 12;
            int nb = cur ^ 1;
            const u16* gk = Kbh + tb + (2*w)*512 + lane*8;
            const u16* gv = Vbh + tb + (2*w)*512 + lane*8;
            gload16(gk,       &lds[nb*4096 + (2*w)*512]);
            gload16(gk + 512, &lds[nb*4096 + (2*w+1)*512]);
            gload16(gv,       &lds[8192 + nb*4096 + (2*w)*512]);
            gload16(gv + 512, &lds[8192 + nb*4096 + (2*w+1)*512]);
        }

        const u16* Kl = &lds[cur * 4096];
        const u16* Vl = &lds[8192 + cur * 4096];

        #pragma unroll
        for (int nt = 0; nt < 4; nt++) {
            float4 bv = *(const float4*)(bbase + t*64 + nt*16);
            bf16x8 ka0 = *(const bf16x8*)(Kl + (nt*2 + 0)*512 + lane*8);
            bf16x8 ka1 = *(const bf16x8*)(Kl + (nt*2 + 1)*512 + lane*8);
            floatx4 tt;
            tt[0] = bv.x; tt[1] = bv.y; tt[2] = bv.z; tt[3] = bv.w;
            tt = __builtin_amdgcn_mfma_f32_16x16x32_bf16(ka0, qb0, tt, 0, 0, 0);
            tt = __builtin_amdgcn_mfma_f32_16x16x32_bf16(ka1, qb1, tt, 0, 0, 0);
            float p0 = fexp2(tt[0]);
            float p1 = fexp2(tt[1]);
            float p2 = fexp2(tt[2]);
            float p3 = fexp2(tt[3]);
            lsum += (p0 + p1) + (p2 + p3);
            int gx = nt*2 + (quad >> 1);
            uint2 pu;
            pu.x = pack2bf(p0, p1);
            pu.y = pack2bf(p2, p3);
            *(uint2*)(Prow + ((gx ^ swz) << 3) + (quad & 1)*4) = pu;
        }

        #pragma unroll
        for (int g = 0; g < 2; g++) {
            bf16x8 pa = *(const bf16x8*)(Prow + (((g*4 + quad) ^ swz) << 3));
            #pragma unroll
            for (int ct = 0; ct < 4; ct++) {
                bf16x8 vbf = *(const bf16x8*)(Vl + (ct*2 + g)*512 + lane*8);
                o[ct] = __builtin_amdgcn_mfma_f32_16x16x32_bf16(pa, vbf, o[ct], 0, 0, 0);
            }
        }

        __syncthreads();
    }

    lsum += __shfl_xor(lsum, 16);
    lsum += __shfl_xor(lsum, 32);
    float inv = 1.0f / lsum;
    float i0 = __shfl(inv, quad*4 + 0);
    float i1 = __shfl(inv, quad*4 + 1);
    float i2 = __shfl(inv, quad*4 + 2);
    float i3 = __shfl(inv, quad*4 + 3);
    #pragma unroll
    for (int ct = 0; ct < 4; ct++) {
        int col = h * HD + ct*16 + l16;
        long rb = (long)(b * SEQ + q0 + w*16 + quad*4);
        ctx[(rb + 0) * DIM + col] = f2bf(o[ct][0] * i0);
        ctx[(rb + 1) * DIM + col] = f2bf(o[ct][1] * i1);
        ctx[(rb + 2) * DIM + col] = f2bf(o[ct][2] * i2);
        ctx[(rb + 3) * DIM + col] = f2bf(o[ct][3] * i3);
    }
}
#endif

// ---------------- output projection: 64x128 tile, 512 blocks (2/CU) ---------
__global__ __launch_bounds__(256, 4) void gemm_proj(
    const u16* __restrict__ A, const u16* __restrict__ Bt,
    float* __restrict__ Out)
{
    __shared__ u16 ldsA[4096];   // 64 x 64
    __shared__ u16 ldsB[8192];   // 128 x 64

    int n0 = blockIdx.x * 128;
    int m0 = blockIdx.y * 64;
    int tid = threadIdx.x;
    int w = tid >> 6, lane = tid & 63, quad = lane >> 4, l16 = lane & 15;
    int l7 = l16 & 7;

    int sr = lane >> 3, sc = lane & 7, gc = sc ^ sr;
    const u16* gA0 = A  + (long)(m0 + sr) * DIM + gc * 8;
    const u16* gB0 = Bt + (long)(n0 + sr) * DIM + gc * 8;

    floatx4 acc[8];
    #pragma unroll
    for (int nt = 0; nt < 8; nt++) acc[nt] = (floatx4){0.f,0.f,0.f,0.f};

    for (int k0 = 0; k0 < DIM; k0 += 64) {
        gload16(gA0 + (long)(2*w)   * 8 * DIM + k0, &ldsA[(2*w)   * 512]);
        gload16(gA0 + (long)(2*w+1) * 8 * DIM + k0, &ldsA[(2*w+1) * 512]);
        #pragma unroll
        for (int i = 0; i < 4; i++)
            gload16(gB0 + (long)(4*w+i) * 8 * DIM + k0, &ldsB[(4*w+i) * 512]);
        __syncthreads();

        #pragma unroll
        for (int kc = 0; kc < 2; kc++) {
            int swz = ((kc * 4 + quad) ^ l7) * 8;
            bf16x8 af = *(const bf16x8*)&ldsA[(w*16 + l16) * 64 + swz];
            #pragma unroll
            for (int nt = 0; nt < 8; nt++) {
                bf16x8 bfv = *(const bf16x8*)&ldsB[(nt*16 + l16) * 64 + swz];
                acc[nt] = __builtin_amdgcn_mfma_f32_16x16x32_bf16(
                    af, bfv, acc[nt], 0, 0, 0);
            }
        }
        __syncthreads();
    }

    #pragma unroll
    for (int nt = 0; nt < 8; nt++)
        #pragma unroll
        for (int r = 0; r < 4; r++) {
            int row = m0 + w*16 + quad*4 + r;
            int col = n0 + nt*16 + l16;
            Out[(long)row * DIM + col] = acc[nt][r];
        }
}

extern "C" void kernel_launch(void* const* d_in, const int* in_sizes, int n_in,
                              void* d_out, int out_size, void* d_ws, size_t ws_size,
                              hipStream_t stream) {
    const float* x  = (const float*)d_in[0];
    const float* Wq = (const float*)d_in[1];
    const float* Wk = (const float*)d_in[2];
    const float* Wv = (const float*)d_in[3];
    const float* Wo = (const float*)d_in[4];
    const int* mask = (const int*)d_in[5];
    float* out = (float*)d_out;

    char* ws = (char*)d_ws;
    size_t off = 0;
    u16* xb  = (u16*)(ws + off); off += (size_t)ROWS * DIM * 2;
    u16* wqb = (u16*)(ws + off); off += (size_t)DIM * DIM * 2;   // wq/wk/wv contiguous = Wcat
    u16* wkb = (u16*)(ws + off); off += (size_t)DIM * DIM * 2;
    u16* wvb = (u16*)(ws + off); off += (size_t)DIM * DIM * 2;
    u16* wob = (u16*)(ws + off); off += (size_t)DIM * DIM * 2;
    u16* Qh  = (u16*)(ws + off); off += (size_t)ROWS * DIM * 2;
    u16* Kfr = (u16*)(ws + off); off += (size_t)ROWS * DIM * 2;
    u16* Vfr = (u16*)(ws + off); off += (size_t)ROWS * DIM * 2;
    u16* ctx = (u16*)(ws + off); off += (size_t)ROWS * DIM * 2;
    float* biasf = (float*)(ws + off); off += (size_t)BS * SEQ * 4;

    convert_all<<<5128, 256, 0, stream>>>(x, Wq, Wk, Wv, Wo, mask,
                                          xb, wqb, wkb, wvb, wob, biasf);
    gemm_qkv_fused<<<dim3(12, 64), 256, 0, stream>>>(xb, wqb, Qh, Kfr, Vfr);
    flash_attn<<<BS * HEADS * (SEQ / 64), 256, 0, stream>>>(Qh, Kfr, Vfr, biasf, ctx);
    gemm_proj<<<dim3(4, 128), 256, 0, stream>>>(ctx, wob, out);

    (void)in_sizes; (void)n_in; (void)out_size; (void)ws_size;
}

// Round 11
// 161.176 us; speedup vs baseline: 1.0283x; 1.0283x over previous
//
#include <hip/hip_runtime.h>
#include <hip/hip_bf16.h>

#define BS 4
#define SEQ 2048
#define DIM 512
#define HEADS 8
#define HD 64
#define ROWS (BS*SEQ)   // 8192
// (1/sqrt(64)) * log2(e) folded into K at projection time
#define SCL2E 0.1803368801111244f
#define NEGB (-1.4426950408889634e6f)   // -1e6 * log2(e)

typedef __attribute__((ext_vector_type(8))) short bf16x8;
typedef __attribute__((ext_vector_type(4))) short bf16x4;
typedef __attribute__((ext_vector_type(4))) float floatx4;
typedef unsigned short u16;
typedef unsigned int u32;

#if defined(__has_builtin)
# if __has_builtin(__builtin_amdgcn_mfma_f32_16x16x16bf16_1k)
#  define HAVE_MFMA16 1
# endif
#endif
#ifndef HAVE_MFMA16
# define HAVE_MFMA16 0
#endif

__device__ __forceinline__ u16 f2bf(float f) {
    union { float f; unsigned u; } v; v.f = f;
    unsigned r = v.u + 0x7fff + ((v.u >> 16) & 1);
    return (u16)(r >> 16);
}

__device__ __forceinline__ unsigned pack2bf(float a, float b) {
#if __has_builtin(__builtin_amdgcn_cvt_pk_bf16_f32)
    typedef __attribute__((ext_vector_type(2))) __bf16 bf2;
    union { bf2 v; unsigned u; } cv;
    cv.v = __builtin_amdgcn_cvt_pk_bf16_f32(a, b);
    return cv.u;
#else
    return (unsigned)f2bf(a) | ((unsigned)f2bf(b) << 16);
#endif
}

__device__ __forceinline__ float fexp2(float x) {
#if __has_builtin(__builtin_amdgcn_exp2f)
    return __builtin_amdgcn_exp2f(x);     // raw v_exp_f32
#else
    return __expf(x * 0.6931471805599453f);
#endif
}

// async global->LDS, 16B per lane. g is PER-LANE global addr, l is wave-uniform.
__device__ __forceinline__ void gload16(const u16* g, u16* l) {
    __builtin_amdgcn_global_load_lds(
        (const __attribute__((address_space(1))) u32*)g,
        (__attribute__((address_space(3))) u32*)l, 16, 0, 0);
}

// ---------------- fp32 -> bf16 conversion; mask -> exp2-domain bias ---------
__global__ __launch_bounds__(256) void convert_all(
    const float* __restrict__ x, const float* __restrict__ Wq,
    const float* __restrict__ Wk, const float* __restrict__ Wv,
    const float* __restrict__ Wo, const int* __restrict__ mask,
    u16* __restrict__ xb, u16* __restrict__ wqb,
    u16* __restrict__ wkb, u16* __restrict__ wvb,
    u16* __restrict__ wob, float* __restrict__ biasf)
{
    int i = blockIdx.x * 256 + threadIdx.x;
    if (i < 1048576 + 262144) {
        const float* src; u16* dst; int off;
        if (i < 1048576) { src = x; dst = xb; off = i; }
        else {
            int j = i - 1048576; int seg = j >> 16; off = j & 65535;
            src = seg == 0 ? Wq : seg == 1 ? Wk : seg == 2 ? Wv : Wo;
            dst = seg == 0 ? wqb : seg == 1 ? wkb : seg == 2 ? wvb : wob;
        }
        float4 v = ((const float4*)src)[off];
        ushort4 o;
        o.x = f2bf(v.x); o.y = f2bf(v.y); o.z = f2bf(v.z); o.w = f2bf(v.w);
        ((ushort4*)dst)[off] = o;
    } else {
        int jb = i - 1310720;                      // 0..2047
        int4 mv = ((const int4*)mask)[jb];
        float4 bo;
        bo.x = (mv.x == 1) ? 0.f : NEGB;
        bo.y = (mv.y == 1) ? 0.f : NEGB;
        bo.z = (mv.z == 1) ? 0.f : NEGB;
        bo.w = (mv.w == 1) ? 0.f : NEGB;
        ((float4*)biasf)[jb] = bo;
    }
}

// ---------------- fused QKV GEMM: C = x @ [Wq;Wk;Wv]^T ----------------------
// R11: double-buffered LDS staging (prefetch k+1 before computing k -> barrier
// drains a load issued ~400 cyc earlier, not a fresh one) + grid transposed
// to (m, n) so the 12 n-consumers of each A-row-block share one XCD (64%8==0:
// block id n*64+m -> XCD m%8), A fetched ~1x instead of ~8x.
__global__ __launch_bounds__(256, 3) void gemm_qkv_fused(
    const u16* __restrict__ A, const u16* __restrict__ Wcat,
    u16* __restrict__ Oq, u16* __restrict__ Okf, u16* __restrict__ Ovf)
{
    __shared__ u16 ldsA[2][8192];   // 128 rows x 64 per buf
    __shared__ u16 ldsB[2][8192];

    int m0 = blockIdx.x * 128;   // m fastest -> same-XCD share A row-block
    int n0 = blockIdx.y * 128;   // 0..1535
    int tid = threadIdx.x;
    int w = tid >> 6, lane = tid & 63, quad = lane >> 4, l16 = lane & 15;
    int mo = (w & 1) * 64, no = (w >> 1) * 64;
    int l7 = l16 & 7;

    int sr = lane >> 3, sc = lane & 7, gc = sc ^ sr;   // staging row/chunk-swz
    const u16* gA0 = A    + (long)(m0 + sr) * DIM + gc * 8;
    const u16* gB0 = Wcat + (long)(n0 + sr) * DIM + gc * 8;

    floatx4 acc[4][4];
    #pragma unroll
    for (int mt = 0; mt < 4; mt++)
        #pragma unroll
        for (int nt = 0; nt < 4; nt++) acc[mt][nt] = (floatx4){0.f,0.f,0.f,0.f};

    // stage iter 0 into buf 0
    #pragma unroll
    for (int i = 0; i < 4; i++) {
        int ch = w * 4 + i;
        gload16(gA0 + (long)ch * 8 * DIM, &ldsA[0][ch * 512]);
        gload16(gB0 + (long)ch * 8 * DIM, &ldsB[0][ch * 512]);
    }
    __syncthreads();

    for (int it = 0; it < 8; it++) {
        int cur = it & 1;
        // prefetch next K-chunk into the other buffer (in flight over compute)
        if (it < 7) {
            int k0 = (it + 1) * 64, nb = cur ^ 1;
            #pragma unroll
            for (int i = 0; i < 4; i++) {
                int ch = w * 4 + i;
                gload16(gA0 + (long)ch * 8 * DIM + k0, &ldsA[nb][ch * 512]);
                gload16(gB0 + (long)ch * 8 * DIM + k0, &ldsB[nb][ch * 512]);
            }
        }

        #pragma unroll
        for (int kc = 0; kc < 2; kc++) {
            int swz = ((kc * 4 + quad) ^ l7) * 8;
            bf16x8 af[4], bf[4];
            #pragma unroll
            for (int t4 = 0; t4 < 4; t4++) {
                af[t4] = *(const bf16x8*)&ldsA[cur][(mo + t4*16 + l16) * 64 + swz];
                bf[t4] = *(const bf16x8*)&ldsB[cur][(no + t4*16 + l16) * 64 + swz];
            }
            #pragma unroll
            for (int mt = 0; mt < 4; mt++)
                #pragma unroll
                for (int nt = 0; nt < 4; nt++)
                    acc[mt][nt] = __builtin_amdgcn_mfma_f32_16x16x32_bf16(
                        af[mt], bf[nt], acc[mt][nt], 0, 0, 0);
        }
        __syncthreads();   // drains prefetch (had full compute to land); guards reuse
    }

    int seg = n0 >> 9;    // block-uniform: 0=Q 1=K 2=V
    if (seg == 0) {
        #pragma unroll
        for (int mt = 0; mt < 4; mt++)
            #pragma unroll
            for (int nt = 0; nt < 4; nt++)
                #pragma unroll
                for (int r = 0; r < 4; r++) {
                    int row = m0 + mo + mt*16 + quad*4 + r;      // b*SEQ+n
                    int col9 = (n0 + no + nt*16 + l16) & 511;    // h*64+d
                    int b = row >> 11, n = row & 2047, h = col9 >> 6, d = col9 & 63;
                    Oq[(((long)(b * HEADS + h) * SEQ + n) << 6) + d] = f2bf(acc[mt][nt][r]);
                }
    } else if (seg == 1) {
        #pragma unroll
        for (int mt = 0; mt < 4; mt++)
            #pragma unroll
            for (int nt = 0; nt < 4; nt++)
                #pragma unroll
                for (int r = 0; r < 4; r++) {
                    int row = m0 + mo + mt*16 + quad*4 + r;
                    int col9 = (n0 + no + nt*16 + l16) & 511;
                    int b = row >> 11, keyn = row & 2047, h = col9 >> 6, dd = col9 & 63;
                    int kt = keyn >> 6, ntk = (keyn >> 4) & 3, l16k = keyn & 15;
                    int g = dd >> 5, quadk = (dd >> 3) & 3, j = dd & 7;
                    long offv = ((long)((b*HEADS + h)*32 + kt) << 12)
                              + ((ntk*2 + g) << 9) + ((quadk*16 + l16k) << 3) + j;
                    Okf[offv] = f2bf(acc[mt][nt][r] * SCL2E);
                }
    } else {
#if HAVE_MFMA16
        // V in per-lane-32B order:
        //   off = tile*4096 + wf*1024 + (quadf*16 + l16f)*16 + ct*4 + j
        //   element (key = t*64 + wf*16 + quadf*4 + j, d = ct*16 + l16f)
        #pragma unroll
        for (int mt = 0; mt < 4; mt++)
            #pragma unroll
            for (int nt = 0; nt < 4; nt++) {
                int rowb = m0 + mo + mt*16 + quad*4;
                int col9 = (n0 + no + nt*16 + l16) & 511;
                int b = rowb >> 11, keyn = rowb & 2047, h = col9 >> 6, dd = col9 & 63;
                int kt = keyn >> 6;
                int wf = (keyn >> 4) & 3, quadf = (keyn >> 2) & 3;   // j = r
                int ctf = dd >> 4, l16f = dd & 15;
                long offv = ((long)((b*HEADS + h)*32 + kt) << 12)
                          + (wf << 10) + ((quadf*16 + l16f) << 4) + (ctf << 2);
                ushort4 st;
                st.x = f2bf(acc[mt][nt][0]); st.y = f2bf(acc[mt][nt][1]);
                st.z = f2bf(acc[mt][nt][2]); st.w = f2bf(acc[mt][nt][3]);
                *(ushort4*)&Ovf[offv] = st;
            }
#else
        #pragma unroll
        for (int mt = 0; mt < 4; mt++)
            #pragma unroll
            for (int nt = 0; nt < 4; nt++) {
                int rowb = m0 + mo + mt*16 + quad*4;
                int col9 = (n0 + no + nt*16 + l16) & 511;
                int b = rowb >> 11, keyn = rowb & 2047, h = col9 >> 6, dd = col9 & 63;
                int kt = keyn >> 6, g = (keyn >> 5) & 1, quadv = (keyn >> 3) & 3, jk = keyn & 7;
                int ctv = dd >> 4, l16v = dd & 15;
                long offv = ((long)((b*HEADS + h)*32 + kt) << 12)
                          + ((ctv*2 + g) << 9) + ((quadv*16 + l16v) << 3) + jk;
                ushort4 st;
                st.x = f2bf(acc[mt][nt][0]); st.y = f2bf(acc[mt][nt][1]);
                st.z = f2bf(acc[mt][nt][2]); st.w = f2bf(acc[mt][nt][3]);
                *(ushort4*)&Ovf[offv] = st;
            }
#endif
    }
}

#if HAVE_MFMA16
// ---------------- flash attention: key-split, register-direct (R8, proven) --
__global__ __launch_bounds__(256, 3) void flash_attn(
    const u16* __restrict__ Q, const u16* __restrict__ Kf,
    const u16* __restrict__ Vf, const float* __restrict__ biasf,
    u16* __restrict__ ctx)
{
    __shared__ float red[4352];   // [0,4096) O slots (1024 floatx4), [4096,4352) lsum

    int bx = blockIdx.x;
    // decode XCD swizzle: bx = (g&7) + 8*((g>>3)*32 + i), g = b*8+h, i = q-block
    int c  = bx & 7, s = bx >> 3;
    int g  = ((s >> 5) << 3) | c;
    int i  = s & 31;
    int q0 = i * 64;
    int h  = g & 7;
    int b  = g >> 3;
    int bh = b * HEADS + h;

    int tid = threadIdx.x;
    int w = tid >> 6, lane = tid & 63, quad = lane >> 4, l16 = lane & 15;

    // Q B-frags for all 4 q-tiles (wave needs all 64 q)
    bf16x8 qb[4][2];
    #pragma unroll
    for (int nt = 0; nt < 4; nt++) {
        const u16* qp = Q + ((long)bh * SEQ + q0 + nt*16 + l16) * HD + quad * 8;
        qb[nt][0] = *(const bf16x8*)(qp);
        qb[nt][1] = *(const bf16x8*)(qp + 32);
    }

    const u16* Kbh = Kf + ((long)bh << 17) + w*1024 + lane*8;    // + t*4096
    const u16* Vbh = Vf + ((long)bh << 17) + w*1024 + lane*16;   // + t*4096
    const float* bb = biasf + b * SEQ + w*16 + quad*4;           // + t*64

    // ones-column B operand: 1.0 only for n == 0 (lanes l16==0), all k
    short one_s = (l16 == 0) ? (short)0x3F80 : (short)0;
    bf16x4 onesb = { one_s, one_s, one_s, one_s };

    // rolling preload: tile 0
    bf16x8 ka0 = *(const bf16x8*)(Kbh);
    bf16x8 ka1 = *(const bf16x8*)(Kbh + 512);
    bf16x8 vlo = *(const bf16x8*)(Vbh);
    bf16x8 vhi = *(const bf16x8*)(Vbh + 8);
    float4 bv  = *(const float4*)(bb);

    floatx4 o[4][4];
    floatx4 o5[4];
    #pragma unroll
    for (int nt = 0; nt < 4; nt++) {
        #pragma unroll
        for (int ct = 0; ct < 4; ct++) o[nt][ct] = (floatx4){0.f,0.f,0.f,0.f};
        o5[nt] = (floatx4){0.f,0.f,0.f,0.f};
    }

    #pragma unroll 2
    for (int t = 0; t < 32; t++) {
        // prefetch next tile into fresh registers (compiler emits vmcnt(N))
        bf16x8 ka0n = ka0, ka1n = ka1, vlon = vlo, vhin = vhi;
        float4 bvn = bv;
        if (t < 31) {
            const u16* kp = Kbh + (long)(t+1)*4096;
            const u16* vp = Vbh + (long)(t+1)*4096;
            ka0n = *(const bf16x8*)(kp);
            ka1n = *(const bf16x8*)(kp + 512);
            vlon = *(const bf16x8*)(vp);
            vhin = *(const bf16x8*)(vp + 8);
            bvn  = *(const float4*)(bb + (t+1)*64);
        }

        union { bf16x8 v8; bf16x4 v4[2]; } uvl, uvh;
        uvl.v8 = vlo; uvh.v8 = vhi;
        bf16x4 vb[4] = { uvl.v4[0], uvl.v4[1], uvh.v4[0], uvh.v4[1] };

        #pragma unroll
        for (int nt = 0; nt < 4; nt++) {
            // S^T[16key][16q] = K.Q^T + bias (C-init; key=quad*4+r, q=l16)
            floatx4 s2;
            s2[0] = bv.x; s2[1] = bv.y; s2[2] = bv.z; s2[3] = bv.w;
            s2 = __builtin_amdgcn_mfma_f32_16x16x32_bf16(ka0, qb[nt][0], s2, 0, 0, 0);
            s2 = __builtin_amdgcn_mfma_f32_16x16x32_bf16(ka1, qb[nt][1], s2, 0, 0, 0);
            float p0 = fexp2(s2[0]);
            float p1 = fexp2(s2[1]);
            float p2 = fexp2(s2[2]);
            float p3 = fexp2(s2[3]);
            // C layout (q=l16, key=quad*4+r) == 16x16x16 A layout (m=l16, k=quad*4+j)
            union { bf16x4 v; unsigned u[2]; } pu;
            pu.u[0] = pack2bf(p0, p1);
            pu.u[1] = pack2bf(p2, p3);
            #pragma unroll
            for (int ct = 0; ct < 4; ct++)
                o[nt][ct] = __builtin_amdgcn_mfma_f32_16x16x16bf16_1k(
                    pu.v, vb[ct], o[nt][ct], 0, 0, 0);
            // denominator on the matrix pipe (rows q=quad*4+r at col l16==0)
            o5[nt] = __builtin_amdgcn_mfma_f32_16x16x16bf16_1k(
                pu.v, onesb, o5[nt], 0, 0, 0);
        }

        ka0 = ka0n; ka1 = ka1n; vlo = vlon; vhi = vhin; bv = bvn;
    }

    __syncthreads();
    float* ldsf = red;
    floatx4* ldsv = (floatx4*)red;

    // publish per-(wave, q) partial denominators from lanes l16==0
    if (l16 == 0) {
        #pragma unroll
        for (int nt = 0; nt < 4; nt++)
            #pragma unroll
            for (int r = 0; r < 4; r++)
                ldsf[4096 + w*64 + nt*16 + quad*4 + r] = o5[nt][r];
    }
    __syncthreads();

    // O rotation: 3 rounds; wave w ends owning full O for q-tile nt==w
    #pragma unroll
    for (int i2 = 1; i2 < 4; i2++) {
        int tslot = (w + i2) & 3;          // wave-uniform
        #pragma unroll
        for (int nt = 0; nt < 4; nt++)
            if (nt == tslot) {
                #pragma unroll
                for (int ct = 0; ct < 4; ct++)
                    ldsv[nt*256 + ct*64 + lane] = o[nt][ct];
            }
        __syncthreads();
        #pragma unroll
        for (int nt = 0; nt < 4; nt++)
            if (nt == w) {
                #pragma unroll
                for (int ct = 0; ct < 4; ct++) {
                    floatx4 v = ldsv[nt*256 + ct*64 + lane];
                    o[nt][ct] += v;
                }
            }
        __syncthreads();
    }

    // epilogue: wave w owns q = q0 + w*16 + quad*4 + r; d = ct*16 + l16
    #pragma unroll
    for (int nt = 0; nt < 4; nt++) {
        if (nt != w) continue;            // wave-uniform
        float inv[4];
        #pragma unroll
        for (int r = 0; r < 4; r++) {
            int q = w*16 + quad*4 + r;
            float sden = ldsf[4096 + q] + ldsf[4096 + 64 + q]
                       + ldsf[4096 + 128 + q] + ldsf[4096 + 192 + q];
            inv[r] = 1.0f / sden;
        }
        #pragma unroll
        for (int ct = 0; ct < 4; ct++) {
            int col = h * HD + ct*16 + l16;
            long rb = (long)(b * SEQ + q0 + w*16 + quad*4);
            #pragma unroll
            for (int r = 0; r < 4; r++)
                ctx[(rb + r) * DIM + col] = f2bf(o[nt][ct][r] * inv[r]);
        }
    }
}
#else
// ---------------- fallback: R5 flash attention ------------------------------
__global__ __launch_bounds__(256, 4) void flash_attn(
    const u16* __restrict__ Q, const u16* __restrict__ Kf,
    const u16* __restrict__ Vf, const float* __restrict__ biasf,
    u16* __restrict__ ctx)
{
    __shared__ u16 lds[20480];

    int bx = blockIdx.x;
    int q0 = (bx & 31) * 64;
    int h  = (bx >> 5) & 7;
    int b  = bx >> 8;
    int bh = b * HEADS + h;

    int tid = threadIdx.x;
    int w = tid >> 6, lane = tid & 63, quad = lane >> 4, l16 = lane & 15;

    const u16* Qp = Q + ((long)bh * SEQ + q0 + w*16 + l16) * HD + quad * 8;
    bf16x8 qb0 = *(const bf16x8*)(Qp);
    bf16x8 qb1 = *(const bf16x8*)(Qp + 32);

    const u16* Kbh = Kf + ((long)bh << 17);
    const u16* Vbh = Vf + ((long)bh << 17);
    const float* bbase = biasf + b * SEQ + quad * 4;

    u16* Prow = &lds[16384 + w * 1024 + l16 * 64];
    int swz = l16 & 7;

    {
        const u16* gk = Kbh + (2*w)*512 + lane*8;
        const u16* gv = Vbh + (2*w)*512 + lane*8;
        gload16(gk,       &lds[(2*w)*512]);
        gload16(gk + 512, &lds[(2*w+1)*512]);
        gload16(gv,       &lds[8192 + (2*w)*512]);
        gload16(gv + 512, &lds[8192 + (2*w+1)*512]);
    }
    __syncthreads();

    floatx4 o[4];
    #pragma unroll
    for (int ct = 0; ct < 4; ct++) o[ct] = (floatx4){0.f, 0.f, 0.f, 0.f};
    float lsum = 0.f;

    for (int t = 0; t < 32; t++) {
        int cur = t & 1;
        if (t < 31) {
            long tb = (long)(t + 1) << 12;
            int nb = cur ^ 1;
            const u16* gk = Kbh + tb + (2*w)*512 + lane*8;
            const u16* gv = Vbh + tb + (2*w)*512 + lane*8;
            gload16(gk,       &lds[nb*4096 + (2*w)*512]);
            gload16(gk + 512, &lds[nb*4096 + (2*w+1)*512]);
            gload16(gv,       &lds[8192 + nb*4096 + (2*w)*512]);
            gload16(gv + 512, &lds[8192 + nb*4096 + (2*w+1)*512]);
        }

        const u16* Kl = &lds[cur * 4096];
        const u16* Vl = &lds[8192 + cur * 4096];

        #pragma unroll
        for (int nt = 0; nt < 4; nt++) {
            float4 bv = *(const float4*)(bbase + t*64 + nt*16);
            bf16x8 ka0 = *(const bf16x8*)(Kl + (nt*2 + 0)*512 + lane*8);
            bf16x8 ka1 = *(const bf16x8*)(Kl + (nt*2 + 1)*512 + lane*8);
            floatx4 tt;
            tt[0] = bv.x; tt[1] = bv.y; tt[2] = bv.z; tt[3] = bv.w;
            tt = __builtin_amdgcn_mfma_f32_16x16x32_bf16(ka0, qb0, tt, 0, 0, 0);
            tt = __builtin_amdgcn_mfma_f32_16x16x32_bf16(ka1, qb1, tt, 0, 0, 0);
            float p0 = fexp2(tt[0]);
            float p1 = fexp2(tt[1]);
            float p2 = fexp2(tt[2]);
            float p3 = fexp2(tt[3]);
            lsum += (p0 + p1) + (p2 + p3);
            int gx = nt*2 + (quad >> 1);
            uint2 pu;
            pu.x = pack2bf(p0, p1);
            pu.y = pack2bf(p2, p3);
            *(uint2*)(Prow + ((gx ^ swz) << 3) + (quad & 1)*4) = pu;
        }

        #pragma unroll
        for (int g = 0; g < 2; g++) {
            bf16x8 pa = *(const bf16x8*)(Prow + (((g*4 + quad) ^ swz) << 3));
            #pragma unroll
            for (int ct = 0; ct < 4; ct++) {
                bf16x8 vbf = *(const bf16x8*)(Vl + (ct*2 + g)*512 + lane*8);
                o[ct] = __builtin_amdgcn_mfma_f32_16x16x32_bf16(pa, vbf, o[ct], 0, 0, 0);
            }
        }

        __syncthreads();
    }

    lsum += __shfl_xor(lsum, 16);
    lsum += __shfl_xor(lsum, 32);
    float inv = 1.0f / lsum;
    float i0 = __shfl(inv, quad*4 + 0);
    float i1 = __shfl(inv, quad*4 + 1);
    float i2 = __shfl(inv, quad*4 + 2);
    float i3 = __shfl(inv, quad*4 + 3);
    #pragma unroll
    for (int ct = 0; ct < 4; ct++) {
        int col = h * HD + ct*16 + l16;
        long rb = (long)(b * SEQ + q0 + w*16 + quad*4);
        ctx[(rb + 0) * DIM + col] = f2bf(o[ct][0] * i0);
        ctx[(rb + 1) * DIM + col] = f2bf(o[ct][1] * i1);
        ctx[(rb + 2) * DIM + col] = f2bf(o[ct][2] * i2);
        ctx[(rb + 3) * DIM + col] = f2bf(o[ct][3] * i3);
    }
}
#endif

// ---------------- output projection: 64x128 tile, dbuf, transposed grid -----
__global__ __launch_bounds__(256, 4) void gemm_proj(
    const u16* __restrict__ A, const u16* __restrict__ Bt,
    float* __restrict__ Out)
{
    __shared__ u16 ldsA[2][4096];   // 64 x 64 per buf
    __shared__ u16 ldsB[2][8192];   // 128 x 64 per buf

    int m0 = blockIdx.x * 64;       // m fastest -> A row-block stays on one XCD
    int n0 = blockIdx.y * 128;
    int tid = threadIdx.x;
    int w = tid >> 6, lane = tid & 63, quad = lane >> 4, l16 = lane & 15;
    int l7 = l16 & 7;

    int sr = lane >> 3, sc = lane & 7, gc = sc ^ sr;
    const u16* gA0 = A  + (long)(m0 + sr) * DIM + gc * 8;
    const u16* gB0 = Bt + (long)(n0 + sr) * DIM + gc * 8;

    floatx4 acc[8];
    #pragma unroll
    for (int nt = 0; nt < 8; nt++) acc[nt] = (floatx4){0.f,0.f,0.f,0.f};

    // stage iter 0
    gload16(gA0 + (long)(2*w)   * 8 * DIM, &ldsA[0][(2*w)   * 512]);
    gload16(gA0 + (long)(2*w+1) * 8 * DIM, &ldsA[0][(2*w+1) * 512]);
    #pragma unroll
    for (int i = 0; i < 4; i++)
        gload16(gB0 + (long)(4*w+i) * 8 * DIM, &ldsB[0][(4*w+i) * 512]);
    __syncthreads();

    for (int it = 0; it < 8; it++) {
        int cur = it & 1;
        if (it < 7) {
            int k0 = (it + 1) * 64, nb = cur ^ 1;
            gload16(gA0 + (long)(2*w)   * 8 * DIM + k0, &ldsA[nb][(2*w)   * 512]);
            gload16(gA0 + (long)(2*w+1) * 8 * DIM + k0, &ldsA[nb][(2*w+1) * 512]);
            #pragma unroll
            for (int i = 0; i < 4; i++)
                gload16(gB0 + (long)(4*w+i) * 8 * DIM + k0, &ldsB[nb][(4*w+i) * 512]);
        }

        #pragma unroll
        for (int kc = 0; kc < 2; kc++) {
            int swz = ((kc * 4 + quad) ^ l7) * 8;
            bf16x8 af = *(const bf16x8*)&ldsA[cur][(w*16 + l16) * 64 + swz];
            #pragma unroll
            for (int nt = 0; nt < 8; nt++) {
                bf16x8 bfv = *(const bf16x8*)&ldsB[cur][(nt*16 + l16) * 64 + swz];
                acc[nt] = __builtin_amdgcn_mfma_f32_16x16x32_bf16(
                    af, bfv, acc[nt], 0, 0, 0);
            }
        }
        __syncthreads();
    }

    #pragma unroll
    for (int nt = 0; nt < 8; nt++)
        #pragma unroll
        for (int r = 0; r < 4; r++) {
            int row = m0 + w*16 + quad*4 + r;
            int col = n0 + nt*16 + l16;
            Out[(long)row * DIM + col] = acc[nt][r];
        }
}

extern "C" void kernel_launch(void* const* d_in, const int* in_sizes, int n_in,
                              void* d_out, int out_size, void* d_ws, size_t ws_size,
                              hipStream_t stream) {
    const float* x  = (const float*)d_in[0];
    const float* Wq = (const float*)d_in[1];
    const float* Wk = (const float*)d_in[2];
    const float* Wv = (const float*)d_in[3];
    const float* Wo = (const float*)d_in[4];
    const int* mask = (const int*)d_in[5];
    float* out = (float*)d_out;

    char* ws = (char*)d_ws;
    size_t off = 0;
    u16* xb  = (u16*)(ws + off); off += (size_t)ROWS * DIM * 2;
    u16* wqb = (u16*)(ws + off); off += (size_t)DIM * DIM * 2;   // wq/wk/wv contiguous = Wcat
    u16* wkb = (u16*)(ws + off); off += (size_t)DIM * DIM * 2;
    u16* wvb = (u16*)(ws + off); off += (size_t)DIM * DIM * 2;
    u16* wob = (u16*)(ws + off); off += (size_t)DIM * DIM * 2;
    u16* Qh  = (u16*)(ws + off); off += (size_t)ROWS * DIM * 2;
    u16* Kfr = (u16*)(ws + off); off += (size_t)ROWS * DIM * 2;
    u16* Vfr = (u16*)(ws + off); off += (size_t)ROWS * DIM * 2;
    u16* ctx = (u16*)(ws + off); off += (size_t)ROWS * DIM * 2;
    float* biasf = (float*)(ws + off); off += (size_t)BS * SEQ * 4;

    convert_all<<<5128, 256, 0, stream>>>(x, Wq, Wk, Wv, Wo, mask,
                                          xb, wqb, wkb, wvb, wob, biasf);
    gemm_qkv_fused<<<dim3(64, 12), 256, 0, stream>>>(xb, wqb, Qh, Kfr, Vfr);
    flash_attn<<<BS * HEADS * (SEQ / 64), 256, 0, stream>>>(Qh, Kfr, Vfr, biasf, ctx);
    gemm_proj<<<dim3(128, 4), 256, 0, stream>>>(ctx, wob, out);

    (void)in_sizes; (void)n_in; (void)out_size; (void)ws_size;
}

// Round 12
// 159.558 us; speedup vs baseline: 1.0388x; 1.0101x over previous
//
#include <hip/hip_runtime.h>
#include <hip/hip_bf16.h>

#define BS 4
#define SEQ 2048
#define DIM 512
#define HEADS 8
#define HD 64
#define ROWS (BS*SEQ)   // 8192
// (1/sqrt(64)) * log2(e) folded into K at projection time
#define SCL2E 0.1803368801111244f
#define NEGB (-1.4426950408889634e6f)   // -1e6 * log2(e)

typedef __attribute__((ext_vector_type(8))) short bf16x8;
typedef __attribute__((ext_vector_type(4))) short bf16x4;
typedef __attribute__((ext_vector_type(4))) float floatx4;
typedef unsigned short u16;
typedef unsigned int u32;

#if defined(__has_builtin)
# if __has_builtin(__builtin_amdgcn_mfma_f32_16x16x16bf16_1k)
#  define HAVE_MFMA16 1
# endif
#endif
#ifndef HAVE_MFMA16
# define HAVE_MFMA16 0
#endif

__device__ __forceinline__ u16 f2bf(float f) {
    union { float f; unsigned u; } v; v.f = f;
    unsigned r = v.u + 0x7fff + ((v.u >> 16) & 1);
    return (u16)(r >> 16);
}

__device__ __forceinline__ unsigned pack2bf(float a, float b) {
#if __has_builtin(__builtin_amdgcn_cvt_pk_bf16_f32)
    typedef __attribute__((ext_vector_type(2))) __bf16 bf2;
    union { bf2 v; unsigned u; } cv;
    cv.v = __builtin_amdgcn_cvt_pk_bf16_f32(a, b);
    return cv.u;
#else
    return (unsigned)f2bf(a) | ((unsigned)f2bf(b) << 16);
#endif
}

__device__ __forceinline__ float fexp2(float x) {
#if __has_builtin(__builtin_amdgcn_exp2f)
    return __builtin_amdgcn_exp2f(x);     // raw v_exp_f32
#else
    return __expf(x * 0.6931471805599453f);
#endif
}

// async global->LDS, 16B per lane. g is PER-LANE global addr, l is wave-uniform.
__device__ __forceinline__ void gload16(const u16* g, u16* l) {
    __builtin_amdgcn_global_load_lds(
        (const __attribute__((address_space(1))) u32*)g,
        (__attribute__((address_space(3))) u32*)l, 16, 0, 0);
}

// ---------------- fp32 -> bf16 conversion; mask -> exp2-domain bias ---------
__global__ __launch_bounds__(256) void convert_all(
    const float* __restrict__ x, const float* __restrict__ Wq,
    const float* __restrict__ Wk, const float* __restrict__ Wv,
    const float* __restrict__ Wo, const int* __restrict__ mask,
    u16* __restrict__ xb, u16* __restrict__ wqb,
    u16* __restrict__ wkb, u16* __restrict__ wvb,
    u16* __restrict__ wob, float* __restrict__ biasf)
{
    int i = blockIdx.x * 256 + threadIdx.x;
    if (i < 1048576 + 262144) {
        const float* src; u16* dst; int off;
        if (i < 1048576) { src = x; dst = xb; off = i; }
        else {
            int j = i - 1048576; int seg = j >> 16; off = j & 65535;
            src = seg == 0 ? Wq : seg == 1 ? Wk : seg == 2 ? Wv : Wo;
            dst = seg == 0 ? wqb : seg == 1 ? wkb : seg == 2 ? wvb : wob;
        }
        float4 v = ((const float4*)src)[off];
        ushort4 o;
        o.x = f2bf(v.x); o.y = f2bf(v.y); o.z = f2bf(v.z); o.w = f2bf(v.w);
        ((ushort4*)dst)[off] = o;
    } else {
        int jb = i - 1310720;                      // 0..2047
        int4 mv = ((const int4*)mask)[jb];
        float4 bo;
        bo.x = (mv.x == 1) ? 0.f : NEGB;
        bo.y = (mv.y == 1) ? 0.f : NEGB;
        bo.z = (mv.z == 1) ? 0.f : NEGB;
        bo.w = (mv.w == 1) ? 0.f : NEGB;
        ((float4*)biasf)[jb] = bo;
    }
}

// ---------------- fused QKV GEMM: C = x @ [Wq;Wk;Wv]^T ----------------------
// Double-buffered LDS staging + grid (m fastest): the 12 n-consumers of each
// A-row-block share one XCD (64%8==0 -> id mod 8 = m mod 8), A fetched ~1x.
__global__ __launch_bounds__(256, 3) void gemm_qkv_fused(
    const u16* __restrict__ A, const u16* __restrict__ Wcat,
    u16* __restrict__ Oq, u16* __restrict__ Okf, u16* __restrict__ Ovf)
{
    __shared__ u16 ldsA[2][8192];   // 128 rows x 64 per buf
    __shared__ u16 ldsB[2][8192];

    int m0 = blockIdx.x * 128;   // m fastest -> same-XCD share A row-block
    int n0 = blockIdx.y * 128;   // 0..1535
    int tid = threadIdx.x;
    int w = tid >> 6, lane = tid & 63, quad = lane >> 4, l16 = lane & 15;
    int mo = (w & 1) * 64, no = (w >> 1) * 64;
    int l7 = l16 & 7;

    int sr = lane >> 3, sc = lane & 7, gc = sc ^ sr;   // staging row/chunk-swz
    const u16* gA0 = A    + (long)(m0 + sr) * DIM + gc * 8;
    const u16* gB0 = Wcat + (long)(n0 + sr) * DIM + gc * 8;

    floatx4 acc[4][4];
    #pragma unroll
    for (int mt = 0; mt < 4; mt++)
        #pragma unroll
        for (int nt = 0; nt < 4; nt++) acc[mt][nt] = (floatx4){0.f,0.f,0.f,0.f};

    // stage iter 0 into buf 0
    #pragma unroll
    for (int i = 0; i < 4; i++) {
        int ch = w * 4 + i;
        gload16(gA0 + (long)ch * 8 * DIM, &ldsA[0][ch * 512]);
        gload16(gB0 + (long)ch * 8 * DIM, &ldsB[0][ch * 512]);
    }
    __syncthreads();

    for (int it = 0; it < 8; it++) {
        int cur = it & 1;
        // prefetch next K-chunk into the other buffer (in flight over compute)
        if (it < 7) {
            int k0 = (it + 1) * 64, nb = cur ^ 1;
            #pragma unroll
            for (int i = 0; i < 4; i++) {
                int ch = w * 4 + i;
                gload16(gA0 + (long)ch * 8 * DIM + k0, &ldsA[nb][ch * 512]);
                gload16(gB0 + (long)ch * 8 * DIM + k0, &ldsB[nb][ch * 512]);
            }
        }

        #pragma unroll
        for (int kc = 0; kc < 2; kc++) {
            int swz = ((kc * 4 + quad) ^ l7) * 8;
            bf16x8 af[4], bf[4];
            #pragma unroll
            for (int t4 = 0; t4 < 4; t4++) {
                af[t4] = *(const bf16x8*)&ldsA[cur][(mo + t4*16 + l16) * 64 + swz];
                bf[t4] = *(const bf16x8*)&ldsB[cur][(no + t4*16 + l16) * 64 + swz];
            }
            #pragma unroll
            for (int mt = 0; mt < 4; mt++)
                #pragma unroll
                for (int nt = 0; nt < 4; nt++)
                    acc[mt][nt] = __builtin_amdgcn_mfma_f32_16x16x32_bf16(
                        af[mt], bf[nt], acc[mt][nt], 0, 0, 0);
        }
        __syncthreads();   // drains prefetch (had full compute to land); guards reuse
    }

    int seg = n0 >> 9;    // block-uniform: 0=Q 1=K 2=V
    if (seg == 0) {
        #pragma unroll
        for (int mt = 0; mt < 4; mt++)
            #pragma unroll
            for (int nt = 0; nt < 4; nt++)
                #pragma unroll
                for (int r = 0; r < 4; r++) {
                    int row = m0 + mo + mt*16 + quad*4 + r;      // b*SEQ+n
                    int col9 = (n0 + no + nt*16 + l16) & 511;    // h*64+d
                    int b = row >> 11, n = row & 2047, h = col9 >> 6, d = col9 & 63;
                    Oq[(((long)(b * HEADS + h) * SEQ + n) << 6) + d] = f2bf(acc[mt][nt][r]);
                }
    } else if (seg == 1) {
        #pragma unroll
        for (int mt = 0; mt < 4; mt++)
            #pragma unroll
            for (int nt = 0; nt < 4; nt++)
                #pragma unroll
                for (int r = 0; r < 4; r++) {
                    int row = m0 + mo + mt*16 + quad*4 + r;
                    int col9 = (n0 + no + nt*16 + l16) & 511;
                    int b = row >> 11, keyn = row & 2047, h = col9 >> 6, dd = col9 & 63;
                    int kt = keyn >> 6, ntk = (keyn >> 4) & 3, l16k = keyn & 15;
                    int g = dd >> 5, quadk = (dd >> 3) & 3, j = dd & 7;
                    long offv = ((long)((b*HEADS + h)*32 + kt) << 12)
                              + ((ntk*2 + g) << 9) + ((quadk*16 + l16k) << 3) + j;
                    Okf[offv] = f2bf(acc[mt][nt][r] * SCL2E);
                }
    } else {
#if HAVE_MFMA16
        // V in per-lane-32B order:
        //   off = tile*4096 + wf*1024 + (quadf*16 + l16f)*16 + ct*4 + j
        //   element (key = t*64 + wf*16 + quadf*4 + j, d = ct*16 + l16f)
        #pragma unroll
        for (int mt = 0; mt < 4; mt++)
            #pragma unroll
            for (int nt = 0; nt < 4; nt++) {
                int rowb = m0 + mo + mt*16 + quad*4;
                int col9 = (n0 + no + nt*16 + l16) & 511;
                int b = rowb >> 11, keyn = rowb & 2047, h = col9 >> 6, dd = col9 & 63;
                int kt = keyn >> 6;
                int wf = (keyn >> 4) & 3, quadf = (keyn >> 2) & 3;   // j = r
                int ctf = dd >> 4, l16f = dd & 15;
                long offv = ((long)((b*HEADS + h)*32 + kt) << 12)
                          + (wf << 10) + ((quadf*16 + l16f) << 4) + (ctf << 2);
                ushort4 st;
                st.x = f2bf(acc[mt][nt][0]); st.y = f2bf(acc[mt][nt][1]);
                st.z = f2bf(acc[mt][nt][2]); st.w = f2bf(acc[mt][nt][3]);
                *(ushort4*)&Ovf[offv] = st;
            }
#else
        #pragma unroll
        for (int mt = 0; mt < 4; mt++)
            #pragma unroll
            for (int nt = 0; nt < 4; nt++) {
                int rowb = m0 + mo + mt*16 + quad*4;
                int col9 = (n0 + no + nt*16 + l16) & 511;
                int b = rowb >> 11, keyn = rowb & 2047, h = col9 >> 6, dd = col9 & 63;
                int kt = keyn >> 6, g = (keyn >> 5) & 1, quadv = (keyn >> 3) & 3, jk = keyn & 7;
                int ctv = dd >> 4, l16v = dd & 15;
                long offv = ((long)((b*HEADS + h)*32 + kt) << 12)
                          + ((ctv*2 + g) << 9) + ((quadv*16 + l16v) << 3) + jk;
                ushort4 st;
                st.x = f2bf(acc[mt][nt][0]); st.y = f2bf(acc[mt][nt][1]);
                st.z = f2bf(acc[mt][nt][2]); st.w = f2bf(acc[mt][nt][3]);
                *(ushort4*)&Ovf[offv] = st;
            }
#endif
    }
}

#if HAVE_MFMA16
// ---------------- flash attention: key-split, register-direct ---------------
// R12: o5/ones-MFMA dropped; denominator back on VALU (16 adds/tile + end
// shuffles). Frees 16 AGPRs: 84 VGPR + 64 AGPR = 148 <= 512/3 -> target
// 3 blocks/CU so VALU & MFMA pipes overlap across waves (m114).
__global__ __launch_bounds__(256, 3) void flash_attn(
    const u16* __restrict__ Q, const u16* __restrict__ Kf,
    const u16* __restrict__ Vf, const float* __restrict__ biasf,
    u16* __restrict__ ctx)
{
    __shared__ float red[4352];   // [0,4096) O slots (1024 floatx4), [4096,4352) lsum

    int bx = blockIdx.x;
    // decode XCD swizzle: bx = (g&7) + 8*((g>>3)*32 + i), g = b*8+h, i = q-block
    int c  = bx & 7, s = bx >> 3;
    int g  = ((s >> 5) << 3) | c;
    int i  = s & 31;
    int q0 = i * 64;
    int h  = g & 7;
    int b  = g >> 3;
    int bh = b * HEADS + h;

    int tid = threadIdx.x;
    int w = tid >> 6, lane = tid & 63, quad = lane >> 4, l16 = lane & 15;

    // Q B-frags for all 4 q-tiles (wave needs all 64 q)
    bf16x8 qb[4][2];
    #pragma unroll
    for (int nt = 0; nt < 4; nt++) {
        const u16* qp = Q + ((long)bh * SEQ + q0 + nt*16 + l16) * HD + quad * 8;
        qb[nt][0] = *(const bf16x8*)(qp);
        qb[nt][1] = *(const bf16x8*)(qp + 32);
    }

    const u16* Kbh = Kf + ((long)bh << 17) + w*1024 + lane*8;    // + t*4096
    const u16* Vbh = Vf + ((long)bh << 17) + w*1024 + lane*16;   // + t*4096
    const float* bb = biasf + b * SEQ + w*16 + quad*4;           // + t*64

    // rolling preload: tile 0
    bf16x8 ka0 = *(const bf16x8*)(Kbh);
    bf16x8 ka1 = *(const bf16x8*)(Kbh + 512);
    bf16x8 vlo = *(const bf16x8*)(Vbh);
    bf16x8 vhi = *(const bf16x8*)(Vbh + 8);
    float4 bv  = *(const float4*)(bb);

    floatx4 o[4][4];
    float ls[4] = {0.f, 0.f, 0.f, 0.f};
    #pragma unroll
    for (int nt = 0; nt < 4; nt++)
        #pragma unroll
        for (int ct = 0; ct < 4; ct++) o[nt][ct] = (floatx4){0.f,0.f,0.f,0.f};

    #pragma unroll 2
    for (int t = 0; t < 32; t++) {
        // prefetch next tile into fresh registers (compiler emits vmcnt(N))
        bf16x8 ka0n = ka0, ka1n = ka1, vlon = vlo, vhin = vhi;
        float4 bvn = bv;
        if (t < 31) {
            const u16* kp = Kbh + (long)(t+1)*4096;
            const u16* vp = Vbh + (long)(t+1)*4096;
            ka0n = *(const bf16x8*)(kp);
            ka1n = *(const bf16x8*)(kp + 512);
            vlon = *(const bf16x8*)(vp);
            vhin = *(const bf16x8*)(vp + 8);
            bvn  = *(const float4*)(bb + (t+1)*64);
        }

        union { bf16x8 v8; bf16x4 v4[2]; } uvl, uvh;
        uvl.v8 = vlo; uvh.v8 = vhi;
        bf16x4 vb[4] = { uvl.v4[0], uvl.v4[1], uvh.v4[0], uvh.v4[1] };

        #pragma unroll
        for (int nt = 0; nt < 4; nt++) {
            // S^T[16key][16q] = K.Q^T + bias (C-init; key=quad*4+r, q=l16)
            floatx4 s2;
            s2[0] = bv.x; s2[1] = bv.y; s2[2] = bv.z; s2[3] = bv.w;
            s2 = __builtin_amdgcn_mfma_f32_16x16x32_bf16(ka0, qb[nt][0], s2, 0, 0, 0);
            s2 = __builtin_amdgcn_mfma_f32_16x16x32_bf16(ka1, qb[nt][1], s2, 0, 0, 0);
            float p0 = fexp2(s2[0]);
            float p1 = fexp2(s2[1]);
            float p2 = fexp2(s2[2]);
            float p3 = fexp2(s2[3]);
            ls[nt] += (p0 + p1) + (p2 + p3);
            // C layout (q=l16, key=quad*4+r) == 16x16x16 A layout (m=l16, k=quad*4+j)
            union { bf16x4 v; unsigned u[2]; } pu;
            pu.u[0] = pack2bf(p0, p1);
            pu.u[1] = pack2bf(p2, p3);
            #pragma unroll
            for (int ct = 0; ct < 4; ct++)
                o[nt][ct] = __builtin_amdgcn_mfma_f32_16x16x16bf16_1k(
                    pu.v, vb[ct], o[nt][ct], 0, 0, 0);
        }

        ka0 = ka0n; ka1 = ka1n; vlo = vlon; vhi = vhin; bv = bvn;
    }

    __syncthreads();
    float* ldsf = red;
    floatx4* ldsv = (floatx4*)red;

    // lsum: reduce over quads (lane owns q=l16 partial over this wave's keys)
    #pragma unroll
    for (int nt = 0; nt < 4; nt++) {
        ls[nt] += __shfl_xor(ls[nt], 16);
        ls[nt] += __shfl_xor(ls[nt], 32);
    }
    if (quad == 0) {
        #pragma unroll
        for (int nt = 0; nt < 4; nt++)
            ldsf[4096 + w*64 + nt*16 + l16] = ls[nt];
    }
    __syncthreads();

    // O rotation: 3 rounds; wave w ends owning full O for q-tile nt==w
    #pragma unroll
    for (int i2 = 1; i2 < 4; i2++) {
        int tslot = (w + i2) & 3;          // wave-uniform
        #pragma unroll
        for (int nt = 0; nt < 4; nt++)
            if (nt == tslot) {
                #pragma unroll
                for (int ct = 0; ct < 4; ct++)
                    ldsv[nt*256 + ct*64 + lane] = o[nt][ct];
            }
        __syncthreads();
        #pragma unroll
        for (int nt = 0; nt < 4; nt++)
            if (nt == w) {
                #pragma unroll
                for (int ct = 0; ct < 4; ct++) {
                    floatx4 v = ldsv[nt*256 + ct*64 + lane];
                    o[nt][ct] += v;
                }
            }
        __syncthreads();
    }

    // epilogue: wave w owns q = q0 + w*16 + quad*4 + r; d = ct*16 + l16
    #pragma unroll
    for (int nt = 0; nt < 4; nt++) {
        if (nt != w) continue;            // wave-uniform
        float inv[4];
        #pragma unroll
        for (int r = 0; r < 4; r++) {
            int q = w*16 + quad*4 + r;
            float sden = ldsf[4096 + q] + ldsf[4096 + 64 + q]
                       + ldsf[4096 + 128 + q] + ldsf[4096 + 192 + q];
            inv[r] = 1.0f / sden;
        }
        #pragma unroll
        for (int ct = 0; ct < 4; ct++) {
            int col = h * HD + ct*16 + l16;
            long rb = (long)(b * SEQ + q0 + w*16 + quad*4);
            #pragma unroll
            for (int r = 0; r < 4; r++)
                ctx[(rb + r) * DIM + col] = f2bf(o[nt][ct][r] * inv[r]);
        }
    }
}
#else
// ---------------- fallback: R5 flash attention ------------------------------
__global__ __launch_bounds__(256, 4) void flash_attn(
    const u16* __restrict__ Q, const u16* __restrict__ Kf,
    const u16* __restrict__ Vf, const float* __restrict__ biasf,
    u16* __restrict__ ctx)
{
    __shared__ u16 lds[20480];

    int bx = blockIdx.x;
    int q0 = (bx & 31) * 64;
    int h  = (bx >> 5) & 7;
    int b  = bx >> 8;
    int bh = b * HEADS + h;

    int tid = threadIdx.x;
    int w = tid >> 6, lane = tid & 63, quad = lane >> 4, l16 = lane & 15;

    const u16* Qp = Q + ((long)bh * SEQ + q0 + w*16 + l16) * HD + quad * 8;
    bf16x8 qb0 = *(const bf16x8*)(Qp);
    bf16x8 qb1 = *(const bf16x8*)(Qp + 32);

    const u16* Kbh = Kf + ((long)bh << 17);
    const u16* Vbh = Vf + ((long)bh << 17);
    const float* bbase = biasf + b * SEQ + quad * 4;

    u16* Prow = &lds[16384 + w * 1024 + l16 * 64];
    int swz = l16 & 7;

    {
        const u16* gk = Kbh + (2*w)*512 + lane*8;
        const u16* gv = Vbh + (2*w)*512 + lane*8;
        gload16(gk,       &lds[(2*w)*512]);
        gload16(gk + 512, &lds[(2*w+1)*512]);
        gload16(gv,       &lds[8192 + (2*w)*512]);
        gload16(gv + 512, &lds[8192 + (2*w+1)*512]);
    }
    __syncthreads();

    floatx4 o[4];
    #pragma unroll
    for (int ct = 0; ct < 4; ct++) o[ct] = (floatx4){0.f, 0.f, 0.f, 0.f};
    float lsum = 0.f;

    for (int t = 0; t < 32; t++) {
        int cur = t & 1;
        if (t < 31) {
            long tb = (long)(t + 1) << 12;
            int nb = cur ^ 1;
            const u16* gk = Kbh + tb + (2*w)*512 + lane*8;
            const u16* gv = Vbh + tb + (2*w)*512 + lane*8;
            gload16(gk,       &lds[nb*4096 + (2*w)*512]);
            gload16(gk + 512, &lds[nb*4096 + (2*w+1)*512]);
            gload16(gv,       &lds[8192 + nb*4096 + (2*w)*512]);
            gload16(gv + 512, &lds[8192 + nb*4096 + (2*w+1)*512]);
        }

        const u16* Kl = &lds[cur * 4096];
        const u16* Vl = &lds[8192 + cur * 4096];

        #pragma unroll
        for (int nt = 0; nt < 4; nt++) {
            float4 bv = *(const float4*)(bbase + t*64 + nt*16);
            bf16x8 ka0 = *(const bf16x8*)(Kl + (nt*2 + 0)*512 + lane*8);
            bf16x8 ka1 = *(const bf16x8*)(Kl + (nt*2 + 1)*512 + lane*8);
            floatx4 tt;
            tt[0] = bv.x; tt[1] = bv.y; tt[2] = bv.z; tt[3] = bv.w;
            tt = __builtin_amdgcn_mfma_f32_16x16x32_bf16(ka0, qb0, tt, 0, 0, 0);
            tt = __builtin_amdgcn_mfma_f32_16x16x32_bf16(ka1, qb1, tt, 0, 0, 0);
            float p0 = fexp2(tt[0]);
            float p1 = fexp2(tt[1]);
            float p2 = fexp2(tt[2]);
            float p3 = fexp2(tt[3]);
            lsum += (p0 + p1) + (p2 + p3);
            int gx = nt*2 + (quad >> 1);
            uint2 pu;
            pu.x = pack2bf(p0, p1);
            pu.y = pack2bf(p2, p3);
            *(uint2*)(Prow + ((gx ^ swz) << 3) + (quad & 1)*4) = pu;
        }

        #pragma unroll
        for (int g = 0; g < 2; g++) {
            bf16x8 pa = *(const bf16x8*)(Prow + (((g*4 + quad) ^ swz) << 3));
            #pragma unroll
            for (int ct = 0; ct < 4; ct++) {
                bf16x8 vbf = *(const bf16x8*)(Vl + (ct*2 + g)*512 + lane*8);
                o[ct] = __builtin_amdgcn_mfma_f32_16x16x32_bf16(pa, vbf, o[ct], 0, 0, 0);
            }
        }

        __syncthreads();
    }

    lsum += __shfl_xor(lsum, 16);
    lsum += __shfl_xor(lsum, 32);
    float inv = 1.0f / lsum;
    float i0 = __shfl(inv, quad*4 + 0);
    float i1 = __shfl(inv, quad*4 + 1);
    float i2 = __shfl(inv, quad*4 + 2);
    float i3 = __shfl(inv, quad*4 + 3);
    #pragma unroll
    for (int ct = 0; ct < 4; ct++) {
        int col = h * HD + ct*16 + l16;
        long rb = (long)(b * SEQ + q0 + w*16 + quad*4);
        ctx[(rb + 0) * DIM + col] = f2bf(o[ct][0] * i0);
        ctx[(rb + 1) * DIM + col] = f2bf(o[ct][1] * i1);
        ctx[(rb + 2) * DIM + col] = f2bf(o[ct][2] * i2);
        ctx[(rb + 3) * DIM + col] = f2bf(o[ct][3] * i3);
    }
}
#endif

// ---------------- output projection: 64x128 tile, dbuf, transposed grid -----
__global__ __launch_bounds__(256, 4) void gemm_proj(
    const u16* __restrict__ A, const u16* __restrict__ Bt,
    float* __restrict__ Out)
{
    __shared__ u16 ldsA[2][4096];   // 64 x 64 per buf
    __shared__ u16 ldsB[2][8192];   // 128 x 64 per buf

    int m0 = blockIdx.x * 64;       // m fastest -> A row-block stays on one XCD
    int n0 = blockIdx.y * 128;
    int tid = threadIdx.x;
    int w = tid >> 6, lane = tid & 63, quad = lane >> 4, l16 = lane & 15;
    int l7 = l16 & 7;

    int sr = lane >> 3, sc = lane & 7, gc = sc ^ sr;
    const u16* gA0 = A  + (long)(m0 + sr) * DIM + gc * 8;
    const u16* gB0 = Bt + (long)(n0 + sr) * DIM + gc * 8;

    floatx4 acc[8];
    #pragma unroll
    for (int nt = 0; nt < 8; nt++) acc[nt] = (floatx4){0.f,0.f,0.f,0.f};

    // stage iter 0
    gload16(gA0 + (long)(2*w)   * 8 * DIM, &ldsA[0][(2*w)   * 512]);
    gload16(gA0 + (long)(2*w+1) * 8 * DIM, &ldsA[0][(2*w+1) * 512]);
    #pragma unroll
    for (int i = 0; i < 4; i++)
        gload16(gB0 + (long)(4*w+i) * 8 * DIM, &ldsB[0][(4*w+i) * 512]);
    __syncthreads();

    for (int it = 0; it < 8; it++) {
        int cur = it & 1;
        if (it < 7) {
            int k0 = (it + 1) * 64, nb = cur ^ 1;
            gload16(gA0 + (long)(2*w)   * 8 * DIM + k0, &ldsA[nb][(2*w)   * 512]);
            gload16(gA0 + (long)(2*w+1) * 8 * DIM + k0, &ldsA[nb][(2*w+1) * 512]);
            #pragma unroll
            for (int i = 0; i < 4; i++)
                gload16(gB0 + (long)(4*w+i) * 8 * DIM + k0, &ldsB[nb][(4*w+i) * 512]);
        }

        #pragma unroll
        for (int kc = 0; kc < 2; kc++) {
            int swz = ((kc * 4 + quad) ^ l7) * 8;
            bf16x8 af = *(const bf16x8*)&ldsA[cur][(w*16 + l16) * 64 + swz];
            #pragma unroll
            for (int nt = 0; nt < 8; nt++) {
                bf16x8 bfv = *(const bf16x8*)&ldsB[cur][(nt*16 + l16) * 64 + swz];
                acc[nt] = __builtin_amdgcn_mfma_f32_16x16x32_bf16(
                    af, bfv, acc[nt], 0, 0, 0);
            }
        }
        __syncthreads();
    }

    #pragma unroll
    for (int nt = 0; nt < 8; nt++)
        #pragma unroll
        for (int r = 0; r < 4; r++) {
            int row = m0 + w*16 + quad*4 + r;
            int col = n0 + nt*16 + l16;
            Out[(long)row * DIM + col] = acc[nt][r];
        }
}

extern "C" void kernel_launch(void* const* d_in, const int* in_sizes, int n_in,
                              void* d_out, int out_size, void* d_ws, size_t ws_size,
                              hipStream_t stream) {
    const float* x  = (const float*)d_in[0];
    const float* Wq = (const float*)d_in[1];
    const float* Wk = (const float*)d_in[2];
    const float* Wv = (const float*)d_in[3];
    const float* Wo = (const float*)d_in[4];
    const int* mask = (const int*)d_in[5];
    float* out = (float*)d_out;

    char* ws = (char*)d_ws;
    size_t off = 0;
    u16* xb  = (u16*)(ws + off); off += (size_t)ROWS * DIM * 2;
    u16* wqb = (u16*)(ws + off); off += (size_t)DIM * DIM * 2;   // wq/wk/wv contiguous = Wcat
    u16* wkb = (u16*)(ws + off); off += (size_t)DIM * DIM * 2;
    u16* wvb = (u16*)(ws + off); off += (size_t)DIM * DIM * 2;
    u16* wob = (u16*)(ws + off); off += (size_t)DIM * DIM * 2;
    u16* Qh  = (u16*)(ws + off); off += (size_t)ROWS * DIM * 2;
    u16* Kfr = (u16*)(ws + off); off += (size_t)ROWS * DIM * 2;
    u16* Vfr = (u16*)(ws + off); off += (size_t)ROWS * DIM * 2;
    u16* ctx = (u16*)(ws + off); off += (size_t)ROWS * DIM * 2;
    float* biasf = (float*)(ws + off); off += (size_t)BS * SEQ * 4;

    convert_all<<<5128, 256, 0, stream>>>(x, Wq, Wk, Wv, Wo, mask,
                                          xb, wqb, wkb, wvb, wob, biasf);
    gemm_qkv_fused<<<dim3(64, 12), 256, 0, stream>>>(xb, wqb, Qh, Kfr, Vfr);
    flash_attn<<<BS * HEADS * (SEQ / 64), 256, 0, stream>>>(Qh, Kfr, Vfr, biasf, ctx);
    gemm_proj<<<dim3(128, 4), 256, 0, stream>>>(ctx, wob, out);

    (void)in_sizes; (void)n_in; (void)out_size; (void)ws_size;
}